// Round 13
// baseline (61.667 us; speedup 1.0000x reference)
//
#include <hip/hip_runtime.h>
#include <hip/hip_bf16.h>

#define HC 60
#define WCC 60
#define DD 64
#define NCELL (HC * WCC)      // 3600
#define NBC (4 * NCELL)       // 14400
#define IMG (HC * 8)          // 480
#define MPAD 3840             // 60 * 64 zero-padded rows per batch
#define NXT 60                // 64-row tiles per dim
#define NTILES (NXT * NXT * 4)     // 14400 wave-tiles, ordered (b, x, y)
#define GB 768                // gemm blocks (3/CU, one round)
#define NWAVES (GB * 4)       // 3072
#define WAVES_PER_XCD (NWAVES / 8)   // 384
#define TILES_PER_XCD (NTILES / 8)   // 1800 contiguous (b,x,y) tiles per XCD
#define GPARTS NWAVES

#define CVT_BLOCKS 480        // 4*3840*64/8 / 256
#define VM_BLOCKS 57          // ceil(14400/256)
#define WC_BLOCKS 60          // 4*3840/256
#define PREP_BLOCKS (CVT_BLOCKS + VM_BLOCKS + WC_BLOCKS)   // 597

typedef __bf16 bf16x8 __attribute__((ext_vector_type(8)));
typedef float f32x4 __attribute__((ext_vector_type(4)));
typedef unsigned short u16x8 __attribute__((ext_vector_type(8)));

__device__ inline unsigned short f2bf(float f) {
    union { float f; unsigned u; } x; x.f = f;
    unsigned u = x.u;
    unsigned r = (u + 0x7fffu + ((u >> 16) & 1u)) >> 16;  // RNE
    return (unsigned short)r;
}

__device__ inline int div60(int v) { return (v * 17477) >> 20; }  // exact for 0<=v<3840

// ---- kernel 1 (fused prep): f32->bf16 convert (padded), vm + partial sum, warped centers ----
__global__ __launch_bounds__(256) void dl_prep_kernel(
    const float* __restrict__ desc, const float* __restrict__ wdesc,
    const float* __restrict__ homog, const float* __restrict__ mask,
    unsigned short* __restrict__ descb, unsigned short* __restrict__ wdescb,
    float* __restrict__ vm, float* __restrict__ vpart, float2* __restrict__ wcent)
{
    const int bid = blockIdx.x;
    const int tid = threadIdx.x;

    if (bid < CVT_BLOCKS) {
        int t = bid * 256 + tid;
        int brow = t >> 3;
        int col = (t & 7) * 8;
        int b = brow / MPAD;
        int row = brow - b * MPAD;
        u16x8 oa = (u16x8)0, ob = (u16x8)0;
        if (row < NCELL) {
            size_t src = ((size_t)(b * NCELL + row)) * DD + col;
            float4 a0 = *(const float4*)(desc + src);
            float4 a1 = *(const float4*)(desc + src + 4);
            float4 b0 = *(const float4*)(wdesc + src);
            float4 b1 = *(const float4*)(wdesc + src + 4);
            oa[0] = f2bf(a0.x); oa[1] = f2bf(a0.y); oa[2] = f2bf(a0.z); oa[3] = f2bf(a0.w);
            oa[4] = f2bf(a1.x); oa[5] = f2bf(a1.y); oa[6] = f2bf(a1.z); oa[7] = f2bf(a1.w);
            ob[0] = f2bf(b0.x); ob[1] = f2bf(b0.y); ob[2] = f2bf(b0.z); ob[3] = f2bf(b0.w);
            ob[4] = f2bf(b1.x); ob[5] = f2bf(b1.y); ob[6] = f2bf(b1.z); ob[7] = f2bf(b1.w);
        }
        size_t dst = (size_t)brow * DD + col;
        *(u16x8*)(descb + dst) = oa;
        *(u16x8*)(wdescb + dst) = ob;
    } else if (bid < CVT_BLOCKS + VM_BLOCKS) {
        int vb = bid - CVT_BLOCKS;
        int cell = vb * 256 + tid;
        float v = 0.f;
        if (cell < NBC) {
            int b = cell / NCELL;
            int rem = cell % NCELL;
            int k = rem / WCC, l = rem % WCC;
            const float* p = mask + (size_t)b * IMG * IMG + (size_t)(k * 8) * IMG + l * 8;
            float prod = 1.f;
#pragma unroll
            for (int dy = 0; dy < 8; ++dy) {
                float4 a0 = *(const float4*)(p + (size_t)dy * IMG);
                float4 a1 = *(const float4*)(p + (size_t)dy * IMG + 4);
                prod *= a0.x * a0.y * a0.z * a0.w * a1.x * a1.y * a1.z * a1.w;
            }
            vm[cell] = prod;
            v = prod;
        }
#pragma unroll
        for (int off = 32; off > 0; off >>= 1) v += __shfl_xor(v, off);
        __shared__ float sp[4];
        if ((tid & 63) == 0) sp[tid >> 6] = v;
        __syncthreads();
        if (tid == 0) vpart[vb] = sp[0] + sp[1] + sp[2] + sp[3];
    } else {
        int t = (bid - CVT_BLOCKS - VM_BLOCKS) * 256 + tid;   // 0 .. 15359
        int b = t / MPAD;
        int r = t - b * MPAD;
        float2 o;
        if (r < NCELL) {
            int i = div60(r);
            int j = r - i * WCC;
            const float* H = homog + b * 9;
            float x = (float)(j * 8 + 4), y = (float)(i * 8 + 4);
            float X2 = H[6] * x + H[7] * y + H[8];
            o.x = (H[3] * x + H[4] * y + H[5]) / X2;   // wy
            o.y = (H[0] * x + H[1] * y + H[2]) / X2;   // wx
        } else {
            o.x = 1e9f; o.y = 1e9f;                    // pad rows: s = 0 path
        }
        wcent[t] = o;
    }
}

// ---- kernel 2: barrier-free direct-to-register MFMA GEMM, XCD-chunked wave ranges ----
// Each wave owns ~4.7 consecutive (b,x,y)-ordered 64x64 tiles (y fastest); A fragments
// register-resident across its span; B fragments streamed from (XCD-local) L2.
__global__ __launch_bounds__(256, 3) void dl_gemm_loss_kernel(
    const unsigned short* __restrict__ descb, const unsigned short* __restrict__ wdescb,
    const float* __restrict__ vm, const float2* __restrict__ wcent,
    float* __restrict__ gpart)
{
    const int tid = threadIdx.x;
    const int lane = tid & 63;
    const int wv = tid >> 6;
    const int p = blockIdx.x;
    const int xcd = p & 7;                         // dispatch round-robins XCDs
    const int qw = (p >> 3) * 4 + wv;              // 0..383 within this XCD
    const int base = xcd * TILES_PER_XCD;
    const int t0 = base + (TILES_PER_XCD * qw) / WAVES_PER_XCD;
    const int t1 = base + (TILES_PER_XCD * (qw + 1)) / WAVES_PER_XCD;

    const int frow = lane & 15;
    const int kg = (lane >> 4) * 16;               // byte offset of lane's k-group

    bf16x8 afr[2][4];
    float partial = 0.f;
    float wlo = 0.f, whi = 0.f;
    int curax = -1;
    int xb = 0, bb = 0;                            // current A panel (row base, batch)

    for (int t = t0; t < t1; ++t) {
        int b = t / (NXT * NXT);
        int r = t - b * (NXT * NXT);
        int x = r / NXT;
        int y = r - x * NXT;

        if (b * 64 + x != curax) {
            curax = b * 64 + x;
            bb = b; xb = x * 64;
            const unsigned char* gA = (const unsigned char*)descb
                                      + ((size_t)b * MPAD + xb) * 128;
#pragma unroll
            for (int kk = 0; kk < 2; ++kk)
#pragma unroll
                for (int f = 0; f < 4; ++f)
                    afr[kk][f] = *(const bf16x8*)(gA + (size_t)(f * 16 + frow) * 128
                                                  + kk * 64 + kg);
            float wy = wcent[b * MPAD + xb + lane].x;
            wlo = wy; whi = wy;
#pragma unroll
            for (int off = 32; off > 0; off >>= 1) {
                wlo = fminf(wlo, __shfl_xor(wlo, off));
                whi = fmaxf(whi, __shfl_xor(whi, off));
            }
        }

        const unsigned char* gB = (const unsigned char*)wdescb
                                  + ((size_t)b * MPAD + y * 64) * 128;

        // col geometry + vm (independent of matrix loads)
        int n0 = y * 64;
        float cyv[4], cxv[4], vmv[4];
#pragma unroll
        for (int fj = 0; fj < 4; ++fj) {
            int col = n0 + fj * 16 + frow;
            int k = div60(col);
            int l = col - k * WCC;
            cyv[fj] = (float)(k * 8 + 4);
            cxv[fj] = (float)(l * 8 + 4);
            vmv[fj] = (col < NCELL) ? vm[b * NCELL + col] : 0.f;
        }
        float cy0 = (float)(div60(n0) * 8 + 4) - 7.5f;
        float cy1 = (float)(div60(n0 + 63) * 8 + 4) + 7.5f;
        bool full = (whi >= cy0) && (wlo <= cy1);

        f32x4 acc[4][4];
        bf16x8 bfr[4];
        const f32x4 Z = (f32x4)(0.f);
#pragma unroll
        for (int f = 0; f < 4; ++f)
            bfr[f] = *(const bf16x8*)(gB + (size_t)(f * 16 + frow) * 128 + kg);
#pragma unroll
        for (int fi = 0; fi < 4; ++fi)
#pragma unroll
            for (int fj = 0; fj < 4; ++fj)
                acc[fi][fj] = __builtin_amdgcn_mfma_f32_16x16x32_bf16(
                    afr[0][fi], bfr[fj], Z, 0, 0, 0);
#pragma unroll
        for (int f = 0; f < 4; ++f)
            bfr[f] = *(const bf16x8*)(gB + (size_t)(f * 16 + frow) * 128 + 64 + kg);
#pragma unroll
        for (int fi = 0; fi < 4; ++fi)
#pragma unroll
            for (int fj = 0; fj < 4; ++fj)
                acc[fi][fj] = __builtin_amdgcn_mfma_f32_16x16x32_bf16(
                    afr[1][fi], bfr[fj], acc[fi][fj], 0, 0, 0);

        // max-form epilogue: vm*max(dot,0.2); s=1 -> vm*(250*relu(1-dot)+0.2)
        if (full) {
#pragma unroll
            for (int fi = 0; fi < 4; ++fi) {
#pragma unroll
                for (int q = 0; q < 4; ++q) {
                    float2 w2 = wcent[bb * MPAD + xb + fi * 16 + (lane >> 4) * 4 + q];
#pragma unroll
                    for (int fj = 0; fj < 4; ++fj) {
                        float dot = acc[fi][fj][q];
                        float ddy = cyv[fj] - w2.x;
                        float ddx = cxv[fj] - w2.y;
                        float d2 = ddy * ddy + ddx * ddx;
                        float pos = 250.f * fmaxf(1.f - dot, 0.f) + 0.2f;
                        float neg = fmaxf(dot, 0.2f);
                        partial += vmv[fj] * ((d2 <= 56.25f) ? pos : neg);
                    }
                }
            }
        } else {
#pragma unroll
            for (int fj = 0; fj < 4; ++fj) {
                float cs = 0.f;
#pragma unroll
                for (int fi = 0; fi < 4; ++fi)
#pragma unroll
                    for (int q = 0; q < 4; ++q)
                        cs += fmaxf(acc[fi][fj][q], 0.2f);
                partial = fmaf(vmv[fj], cs, partial);
            }
        }
    }

    // per-wave partial -> global (no barriers, no atomics, no fences)
#pragma unroll
    for (int off = 32; off > 0; off >>= 1) partial += __shfl_xor(partial, off);
    if (lane == 0) gpart[p * 4 + wv] = partial;
}

// ---- kernel 3: final reduction -> scalar (applies the -0.2 max-form correction) ----
__global__ __launch_bounds__(256) void dl_final_kernel(
    const float* __restrict__ vpart, const float* __restrict__ gpart,
    float* __restrict__ out)
{
    int tid = threadIdx.x;
    float ls = 0.f, vs = 0.f;
    for (int i = tid; i < GPARTS; i += 256) ls += gpart[i];
    for (int i = tid; i < VM_BLOCKS; i += 256) vs += vpart[i];
#pragma unroll
    for (int off = 32; off > 0; off >>= 1) {
        ls += __shfl_xor(ls, off);
        vs += __shfl_xor(vs, off);
    }
    __shared__ float sl[4], sv[4];
    if ((tid & 63) == 0) { sl[tid >> 6] = ls; sv[tid >> 6] = vs; }
    __syncthreads();
    if (tid == 0) {
        float L = sl[0] + sl[1] + sl[2] + sl[3];
        float V = sv[0] + sv[1] + sv[2] + sv[3];
        L -= 0.2f * (float)MPAD * V;          // max-form global correction (768*V)
        out[0] = L / (V * (float)NCELL);
    }
}

extern "C" void kernel_launch(void* const* d_in, const int* in_sizes, int n_in,
                              void* d_out, int out_size, void* d_ws, size_t ws_size,
                              hipStream_t stream) {
    const float* desc  = (const float*)d_in[0];
    const float* wdesc = (const float*)d_in[1];
    const float* homog = (const float*)d_in[2];
    const float* mask  = (const float*)d_in[3];
    float* out = (float*)d_out;
    float* wsf = (float*)d_ws;

    // workspace layout (floats); every slot fully overwritten each call
    float* vpart = wsf;                           // [57]
    float* vm    = wsf + 64;                      // [14400] -> 14464
    float* gpart = wsf + 14464;                   // [3072]  -> 17536
    float2* wcent = (float2*)(wsf + 17536);       // [4*3840] float2 -> 48256
    unsigned short* descb  = (unsigned short*)(wsf + 48256);   // bf16 [4*3840*64], 256B-aligned
    unsigned short* wdescb = descb + (size_t)4 * MPAD * DD;

    hipLaunchKernelGGL(dl_prep_kernel, dim3(PREP_BLOCKS), dim3(256), 0, stream,
                       desc, wdesc, homog, mask, descb, wdescb, vm, vpart, wcent);
    hipLaunchKernelGGL(dl_gemm_loss_kernel, dim3(GB), dim3(256), 0, stream,
                       descb, wdescb, vm, wcent, gpart);
    hipLaunchKernelGGL(dl_final_kernel, dim3(1), dim3(256), 0, stream,
                       vpart, gpart, out);
}

// Round 14
// 33.572 us; speedup vs baseline: 1.8369x; 1.8369x over previous
//
#include <hip/hip_runtime.h>
#include <hip/hip_bf16.h>

#define HC 60
#define WCC 60
#define DD 64
#define NCELL (HC * WCC)      // 3600
#define NBC (4 * NCELL)       // 14400
#define IMG (HC * 8)          // 480
#define MPAD 3840             // 30 * 128 zero-padded rows per batch
#define NT2 30                // 128-tiles per dim
#define GEMM_BLOCKS (NT2 * NT2 * 4)   // 3600
#define CHUNK (GEMM_BLOCKS / 8)       // 450 tiles per XCD

#define CVT_BLOCKS 480        // 4*3840*64/8 / 256
#define VM_BLOCKS 57          // ceil(14400/256)
#define WC_BLOCKS 60          // 4*3840/256
#define PREP_BLOCKS (CVT_BLOCKS + VM_BLOCKS + WC_BLOCKS)   // 597

typedef __bf16 bf16x8 __attribute__((ext_vector_type(8)));
typedef float f32x4 __attribute__((ext_vector_type(4)));
typedef unsigned short u16x8 __attribute__((ext_vector_type(8)));

__device__ inline unsigned short f2bf(float f) {
    union { float f; unsigned u; } x; x.f = f;
    unsigned u = x.u;
    unsigned r = (u + 0x7fffu + ((u >> 16) & 1u)) >> 16;  // RNE
    return (unsigned short)r;
}

__device__ inline void gload_lds16(const void* g, void* l) {
    __builtin_amdgcn_global_load_lds(
        (const __attribute__((address_space(1))) unsigned int*)g,
        (__attribute__((address_space(3))) unsigned int*)l, 16, 0, 0);
}

__device__ inline int div60(int v) { return (v * 17477) >> 20; }  // exact for 0<=v<3840

// ---- kernel 1 (fused prep): f32->bf16 convert (padded), vm + partial sum, warped centers ----
// cvt work is assigned so its block runs on the SAME XCD that the gemm kernel's
// chunked swizzle will read it from (blockIdx%8 -> XCD round-robin): the converted
// lines stay dirty in that XCD's L2, avoiding the cross-XCD HBM round-trip.
__global__ __launch_bounds__(256) void dl_prep_kernel(
    const float* __restrict__ desc, const float* __restrict__ wdesc,
    const float* __restrict__ homog, const float* __restrict__ mask,
    unsigned short* __restrict__ descb, unsigned short* __restrict__ wdescb,
    float* __restrict__ vm, float* __restrict__ vpart, float2* __restrict__ wcent)
{
    const int bid = blockIdx.x;
    const int tid = threadIdx.x;

    if (bid < CVT_BLOCKS) {
        // consumer-XCD-aligned work mapping:
        // k = bid&7 = consumer XCD = 2*b + (x>=15); q = bid>>3 in [0,60)
        int k = bid & 7;
        int q = bid >> 3;
        int b = k >> 1;
        int wp = (k & 1) * 60 + q;            // 32-row chunk index within batch, [0,120)
        int row = wp * 32 + (tid >> 3);       // row within batch, [0,3840)
        int col = (tid & 7) * 8;
        u16x8 oa = (u16x8)0, ob = (u16x8)0;
        if (row < NCELL) {
            size_t src = ((size_t)(b * NCELL + row)) * DD + col;
            float4 a0 = *(const float4*)(desc + src);
            float4 a1 = *(const float4*)(desc + src + 4);
            float4 b0 = *(const float4*)(wdesc + src);
            float4 b1 = *(const float4*)(wdesc + src + 4);
            oa[0] = f2bf(a0.x); oa[1] = f2bf(a0.y); oa[2] = f2bf(a0.z); oa[3] = f2bf(a0.w);
            oa[4] = f2bf(a1.x); oa[5] = f2bf(a1.y); oa[6] = f2bf(a1.z); oa[7] = f2bf(a1.w);
            ob[0] = f2bf(b0.x); ob[1] = f2bf(b0.y); ob[2] = f2bf(b0.z); ob[3] = f2bf(b0.w);
            ob[4] = f2bf(b1.x); ob[5] = f2bf(b1.y); ob[6] = f2bf(b1.z); ob[7] = f2bf(b1.w);
        }
        size_t dst = ((size_t)b * MPAD + row) * DD + col;
        *(u16x8*)(descb + dst) = oa;
        *(u16x8*)(wdescb + dst) = ob;
    } else if (bid < CVT_BLOCKS + VM_BLOCKS) {
        int vb = bid - CVT_BLOCKS;
        int cell = vb * 256 + tid;
        float v = 0.f;
        if (cell < NBC) {
            int b = cell / NCELL;
            int rem = cell % NCELL;
            int k = rem / WCC, l = rem % WCC;
            const float* p = mask + (size_t)b * IMG * IMG + (size_t)(k * 8) * IMG + l * 8;
            float prod = 1.f;
#pragma unroll
            for (int dy = 0; dy < 8; ++dy) {
                float4 a0 = *(const float4*)(p + (size_t)dy * IMG);
                float4 a1 = *(const float4*)(p + (size_t)dy * IMG + 4);
                prod *= a0.x * a0.y * a0.z * a0.w * a1.x * a1.y * a1.z * a1.w;
            }
            vm[cell] = prod;
            v = prod;
        }
#pragma unroll
        for (int off = 32; off > 0; off >>= 1) v += __shfl_xor(v, off);
        __shared__ float sp[4];
        if ((tid & 63) == 0) sp[tid >> 6] = v;
        __syncthreads();
        if (tid == 0) vpart[vb] = sp[0] + sp[1] + sp[2] + sp[3];
    } else {
        int t = (bid - CVT_BLOCKS - VM_BLOCKS) * 256 + tid;   // 0 .. 15359
        int b = t / MPAD;
        int r = t - b * MPAD;
        float2 o;
        if (r < NCELL) {
            int i = div60(r);
            int j = r - i * WCC;
            const float* H = homog + b * 9;
            float x = (float)(j * 8 + 4), y = (float)(i * 8 + 4);
            float X2 = H[6] * x + H[7] * y + H[8];
            o.x = (H[3] * x + H[4] * y + H[5]) / X2;   // wy
            o.y = (H[0] * x + H[1] * y + H[2]) / X2;   // wx
        } else {
            o.x = 1e9f; o.y = 1e9f;                    // pad rows: s = 0, simple path
        }
        wcent[t] = o;
    }
}

// ---- kernel 2: 128x128-tile GEMM with fused max-form loss epilogue (XCD-chunked order) ----
__global__ __launch_bounds__(256, 3) void dl_gemm_loss_kernel(
    const unsigned short* __restrict__ descb, const unsigned short* __restrict__ wdescb,
    const float* __restrict__ vm, const float2* __restrict__ wcent,
    float* __restrict__ gpart)
{
    __shared__ unsigned char sA[128 * 128];   // 128 rows x 64 bf16, XOR-swizzled
    __shared__ unsigned char sB[128 * 128];
    __shared__ float2 swc[128];
    __shared__ float swave[4];

    // T1 chunked-bijective XCD swizzle (8 | 3600): XCD owns 450 contiguous
    // (b, x, y)-ordered tiles (y fastest) -> per-XCD hot set ~1 MB, L2-resident.
    const int orig = blockIdx.x;
    const int tile = (orig & 7) * CHUNK + (orig >> 3);
    const int b = tile / (NT2 * NT2);
    const int rr = tile - b * (NT2 * NT2);
    const int x = rr / NT2;
    const int y = rr - x * NT2;
    const int m0 = x * 128;
    const int n0 = y * 128;

    const int tid = threadIdx.x;
    const int lane = tid & 63;
    const int wv = tid >> 6;                  // 0..3

    const unsigned char* gA = (const unsigned char*)(descb + (size_t)b * MPAD * DD) + (size_t)m0 * 128;
    const unsigned char* gB = (const unsigned char*)(wdescb + (size_t)b * MPAD * DD) + (size_t)n0 * 128;

    // stage tiles: LDS dest linear, swizzle via pre-swizzled global source (m173)
    {
        const int swz = ((lane & 7) ^ (lane >> 3)) << 4;
        const int lrow = lane >> 3;
#pragma unroll
        for (int t = 0; t < 4; ++t) {
            int row = wv * 32 + t * 8 + lrow;
            gload_lds16(gA + (size_t)row * 128 + swz, sA + wv * 4096 + t * 1024);
            gload_lds16(gB + (size_t)row * 128 + swz, sB + wv * 4096 + t * 1024);
        }
    }
    if (tid < 128) swc[tid] = wcent[b * MPAD + m0 + tid];

    const int wr = wv >> 1, wcs = wv & 1;     // wave -> 64x64 subtile
    const int frow = lane & 15;
    const int kg = (lane >> 4) * 16;

    // ---- pre-barrier independent work (hides under staging vmcnt) ----
    float cyv[4], cxv[4], vmv[4];
#pragma unroll
    for (int fj = 0; fj < 4; ++fj) {
        int col = n0 + wcs * 64 + fj * 16 + frow;
        int k = div60(col);
        int l = col - k * WCC;
        cyv[fj] = (float)(k * 8 + 4);
        cxv[fj] = (float)(l * 8 + 4);
        vmv[fj] = (col < NCELL) ? vm[b * NCELL + col] : 0.f;
    }
    // wave-uniform s-possibility test: row wy min/max (from global, not LDS)
    float wyl = wcent[b * MPAD + m0 + wr * 64 + lane].x;
    float wlo = wyl, whi = wyl;
#pragma unroll
    for (int off = 32; off > 0; off >>= 1) {
        wlo = fminf(wlo, __shfl_xor(wlo, off));
        whi = fmaxf(whi, __shfl_xor(whi, off));
    }
    int c0 = n0 + wcs * 64;
    float cy0 = (float)(div60(c0) * 8 + 4) - 7.5f;
    float cy1 = (float)(div60(c0 + 63) * 8 + 4) + 7.5f;
    bool full = (whi >= cy0) && (wlo <= cy1);

    __syncthreads();

    f32x4 acc[4][4];
#pragma unroll
    for (int i2 = 0; i2 < 4; ++i2)
#pragma unroll
        for (int j2 = 0; j2 < 4; ++j2)
            acc[i2][j2] = (f32x4)(0.f);

#pragma unroll
    for (int kk = 0; kk < 2; ++kk) {
        int kbyte = kk * 64 + kg;
        bf16x8 afr[4], bfr[4];
#pragma unroll
        for (int f = 0; f < 4; ++f) {
            int ra = wr * 64 + f * 16 + frow;
            afr[f] = *(const bf16x8*)(sA + ra * 128 + (kbyte ^ ((ra & 7) << 4)));
            int rb = wcs * 64 + f * 16 + frow;
            bfr[f] = *(const bf16x8*)(sB + rb * 128 + (kbyte ^ ((rb & 7) << 4)));
        }
#pragma unroll
        for (int fi = 0; fi < 4; ++fi)
#pragma unroll
            for (int fj = 0; fj < 4; ++fj)
                acc[fi][fj] = __builtin_amdgcn_mfma_f32_16x16x32_bf16(
                    afr[fi], bfr[fj], acc[fi][fj], 0, 0, 0);
    }

    // ---- max-form epilogue: vm*max(dot,0.2); s=1 -> vm*(250*relu(1-dot)+0.2) ----
    float partial = 0.f;
    if (full) {
#pragma unroll
        for (int fi = 0; fi < 4; ++fi) {
#pragma unroll
            for (int q = 0; q < 4; ++q) {
                float2 w2 = swc[wr * 64 + fi * 16 + (lane >> 4) * 4 + q];
#pragma unroll
                for (int fj = 0; fj < 4; ++fj) {
                    float dot = acc[fi][fj][q];
                    float ddy = cyv[fj] - w2.x;
                    float ddx = cxv[fj] - w2.y;
                    float d2 = ddy * ddy + ddx * ddx;
                    float pos = 250.f * fmaxf(1.f - dot, 0.f) + 0.2f;
                    float neg = fmaxf(dot, 0.2f);
                    partial += vmv[fj] * ((d2 <= 56.25f) ? pos : neg);
                }
            }
        }
    } else {
#pragma unroll
        for (int fj = 0; fj < 4; ++fj) {
            float cs = 0.f;
#pragma unroll
            for (int fi = 0; fi < 4; ++fi)
#pragma unroll
                for (int q = 0; q < 4; ++q)
                    cs += fmaxf(acc[fi][fj][q], 0.2f);
            partial = fmaf(vmv[fj], cs, partial);
        }
    }

#pragma unroll
    for (int off = 32; off > 0; off >>= 1) partial += __shfl_xor(partial, off);
    if (lane == 0) swave[wv] = partial;
    __syncthreads();
    if (tid == 0)
        gpart[orig] = swave[0] + swave[1] + swave[2] + swave[3];
}

// ---- kernel 3: final reduction -> scalar (applies the -0.2 max-form correction) ----
__global__ __launch_bounds__(256) void dl_final_kernel(
    const float* __restrict__ vpart, const float* __restrict__ gpart,
    float* __restrict__ out)
{
    int tid = threadIdx.x;
    float ls = 0.f, vs = 0.f;
    for (int i = tid; i < GEMM_BLOCKS; i += 256) ls += gpart[i];
    for (int i = tid; i < VM_BLOCKS; i += 256) vs += vpart[i];
#pragma unroll
    for (int off = 32; off > 0; off >>= 1) {
        ls += __shfl_xor(ls, off);
        vs += __shfl_xor(vs, off);
    }
    __shared__ float sl[4], sv[4];
    if ((tid & 63) == 0) { sl[tid >> 6] = ls; sv[tid >> 6] = vs; }
    __syncthreads();
    if (tid == 0) {
        float L = sl[0] + sl[1] + sl[2] + sl[3];
        float V = sv[0] + sv[1] + sv[2] + sv[3];
        L -= 0.2f * (float)MPAD * V;          // max-form global correction (768*V)
        out[0] = L / (V * (float)NCELL);
    }
}

extern "C" void kernel_launch(void* const* d_in, const int* in_sizes, int n_in,
                              void* d_out, int out_size, void* d_ws, size_t ws_size,
                              hipStream_t stream) {
    const float* desc  = (const float*)d_in[0];
    const float* wdesc = (const float*)d_in[1];
    const float* homog = (const float*)d_in[2];
    const float* mask  = (const float*)d_in[3];
    float* out = (float*)d_out;
    float* wsf = (float*)d_ws;

    // workspace layout (floats); every slot fully overwritten each call
    float* vpart = wsf;                           // [57]
    float* vm    = wsf + 64;                      // [14400]
    float* gpart = wsf + 64 + NBC;                // [3600] -> ends at 18064
    float2* wcent = (float2*)(wsf + 18064);       // [4*3840] float2, 8B aligned
    unsigned short* descb  = (unsigned short*)(wsf + 48896);   // bf16 [4*3840*64]
    unsigned short* wdescb = descb + (size_t)4 * MPAD * DD;

    hipLaunchKernelGGL(dl_prep_kernel, dim3(PREP_BLOCKS), dim3(256), 0, stream,
                       desc, wdesc, homog, mask, descb, wdescb, vm, vpart, wcent);
    hipLaunchKernelGGL(dl_gemm_loss_kernel, dim3(GEMM_BLOCKS), dim3(256), 0, stream,
                       descb, wdescb, vm, wcent, gpart);
    hipLaunchKernelGGL(dl_final_kernel, dim3(1), dim3(256), 0, stream,
                       vpart, gpart, out);
}

// Round 15
// 31.596 us; speedup vs baseline: 1.9517x; 1.0625x over previous
//
#include <hip/hip_runtime.h>
#include <hip/hip_bf16.h>
#include <hip/hip_fp8.h>

#define HC 60
#define WCC 60
#define DD 64
#define NCELL (HC * WCC)      // 3600
#define NBC (4 * NCELL)       // 14400
#define IMG (HC * 8)          // 480
#define MPAD 3840             // 30 * 128 zero-padded rows per batch
#define NT2 30                // 128-tiles per dim
#define GEMM_BLOCKS (NT2 * NT2 * 4)   // 3600
#define CHUNK (GEMM_BLOCKS / 8)       // 450 tiles per XCD

#define CVT_BLOCKS 480        // 4*3840*64/8 / 256
#define VM_BLOCKS 57          // ceil(14400/256)
#define WC_BLOCKS 60          // 4*3840/256
#define PREP_BLOCKS (CVT_BLOCKS + VM_BLOCKS + WC_BLOCKS)   // 597

typedef float f32x4 __attribute__((ext_vector_type(4)));
typedef unsigned long long u64x2 __attribute__((ext_vector_type(2)));

__device__ inline unsigned char f2fp8(float f) {
    __hip_fp8_e4m3 h(f);                  // OCP e4m3fn, RNE + saturate
    return h.__x;
}

__device__ inline void gload_lds16(const void* g, void* l) {
    __builtin_amdgcn_global_load_lds(
        (const __attribute__((address_space(1))) unsigned int*)g,
        (__attribute__((address_space(3))) unsigned int*)l, 16, 0, 0);
}

__device__ inline int div60(int v) { return (v * 17477) >> 20; }  // exact for 0<=v<3840

// fp8 row layout (64 B per row, K=64): group g (16 B) holds k=[g*8,+8) in bytes
// [g*16,+8) and k=[32+g*8,+8) in bytes [g*16+8,+8); whole row pre-swizzled by
// byte ^= (row&3)<<4 so the GEMM can stage it with a pure linear global_load_lds
// and read each lane's (kk0,kk1) fragment pair as ONE 16B LDS read.

// ---- kernel 1 (fused prep): f32 -> fp8 convert (interleaved+swizzled), vm, wcent ----
__global__ __launch_bounds__(256) void dl_prep_kernel(
    const float* __restrict__ desc, const float* __restrict__ wdesc,
    const float* __restrict__ homog, const float* __restrict__ mask,
    unsigned char* __restrict__ descb, unsigned char* __restrict__ wdescb,
    float* __restrict__ vm, float* __restrict__ vpart, float2* __restrict__ wcent)
{
    const int bid = blockIdx.x;
    const int tid = threadIdx.x;

    if (bid < CVT_BLOCKS) {
        // consumer-XCD-aligned mapping (kept from R14; harmless)
        int k = bid & 7;
        int q = bid >> 3;
        int b = k >> 1;
        int wp = (k & 1) * 60 + q;            // 32-row chunk within batch, [0,120)
        int row = wp * 32 + (tid >> 3);       // row within batch, [0,3840)
        int c = tid & 7;                      // 8-value k-chunk index
        unsigned long long pa = 0ull, pb = 0ull;
        if (row < NCELL) {
            size_t src = ((size_t)(b * NCELL + row)) * DD + c * 8;
            float4 a0 = *(const float4*)(desc + src);
            float4 a1 = *(const float4*)(desc + src + 4);
            float4 b0 = *(const float4*)(wdesc + src);
            float4 b1 = *(const float4*)(wdesc + src + 4);
            pa = (unsigned long long)f2fp8(a0.x)
               | ((unsigned long long)f2fp8(a0.y) << 8)
               | ((unsigned long long)f2fp8(a0.z) << 16)
               | ((unsigned long long)f2fp8(a0.w) << 24)
               | ((unsigned long long)f2fp8(a1.x) << 32)
               | ((unsigned long long)f2fp8(a1.y) << 40)
               | ((unsigned long long)f2fp8(a1.z) << 48)
               | ((unsigned long long)f2fp8(a1.w) << 56);
            pb = (unsigned long long)f2fp8(b0.x)
               | ((unsigned long long)f2fp8(b0.y) << 8)
               | ((unsigned long long)f2fp8(b0.z) << 16)
               | ((unsigned long long)f2fp8(b0.w) << 24)
               | ((unsigned long long)f2fp8(b1.x) << 32)
               | ((unsigned long long)f2fp8(b1.y) << 40)
               | ((unsigned long long)f2fp8(b1.z) << 48)
               | ((unsigned long long)f2fp8(b1.w) << 56);
        }
        // interleaved position: chunk c<4 -> byte c*16 ; c>=4 -> (c-4)*16+8 ; then swizzle
        int pos = ((c & 3) * 16 + (c >> 2) * 8) ^ ((row & 3) << 4);
        size_t dst = ((size_t)b * MPAD + row) * 64 + pos;
        *(unsigned long long*)(descb + dst) = pa;
        *(unsigned long long*)(wdescb + dst) = pb;
    } else if (bid < CVT_BLOCKS + VM_BLOCKS) {
        int vb = bid - CVT_BLOCKS;
        int cell = vb * 256 + tid;
        float v = 0.f;
        if (cell < NBC) {
            int b = cell / NCELL;
            int rem = cell % NCELL;
            int k = rem / WCC, l = rem % WCC;
            const float* p = mask + (size_t)b * IMG * IMG + (size_t)(k * 8) * IMG + l * 8;
            float prod = 1.f;
#pragma unroll
            for (int dy = 0; dy < 8; ++dy) {
                float4 a0 = *(const float4*)(p + (size_t)dy * IMG);
                float4 a1 = *(const float4*)(p + (size_t)dy * IMG + 4);
                prod *= a0.x * a0.y * a0.z * a0.w * a1.x * a1.y * a1.z * a1.w;
            }
            vm[cell] = prod;
            v = prod;
        }
#pragma unroll
        for (int off = 32; off > 0; off >>= 1) v += __shfl_xor(v, off);
        __shared__ float sp[4];
        if ((tid & 63) == 0) sp[tid >> 6] = v;
        __syncthreads();
        if (tid == 0) vpart[vb] = sp[0] + sp[1] + sp[2] + sp[3];
    } else {
        int t = (bid - CVT_BLOCKS - VM_BLOCKS) * 256 + tid;   // 0 .. 15359
        int b = t / MPAD;
        int r = t - b * MPAD;
        float2 o;
        if (r < NCELL) {
            int i = div60(r);
            int j = r - i * WCC;
            const float* H = homog + b * 9;
            float x = (float)(j * 8 + 4), y = (float)(i * 8 + 4);
            float X2 = H[6] * x + H[7] * y + H[8];
            o.x = (H[3] * x + H[4] * y + H[5]) / X2;   // wy
            o.y = (H[0] * x + H[1] * y + H[2]) / X2;   // wx
        } else {
            o.x = 1e9f; o.y = 1e9f;                    // pad rows: s = 0, simple path
        }
        wcent[t] = o;
    }
}

// ---- kernel 2: 128x128-tile fp8 GEMM with fused max-form loss epilogue ----
__global__ __launch_bounds__(256, 3) void dl_gemm_loss_kernel(
    const unsigned char* __restrict__ descb, const unsigned char* __restrict__ wdescb,
    const float* __restrict__ vm, const float2* __restrict__ wcent,
    float* __restrict__ gpart)
{
    __shared__ unsigned char sA[128 * 64];    // fp8 tile, 8 KB, pre-swizzled image
    __shared__ unsigned char sB[128 * 64];
    __shared__ float2 swc[128];
    __shared__ float swave[4];

    // T1 chunked-bijective XCD swizzle (8 | 3600)
    const int orig = blockIdx.x;
    const int tile = (orig & 7) * CHUNK + (orig >> 3);
    const int b = tile / (NT2 * NT2);
    const int rr = tile - b * (NT2 * NT2);
    const int x = rr / NT2;
    const int y = rr - x * NT2;
    const int m0 = x * 128;
    const int n0 = y * 128;

    const int tid = threadIdx.x;
    const int lane = tid & 63;
    const int wv = tid >> 6;                  // 0..3

    const unsigned char* gA = descb + ((size_t)b * MPAD + m0) * 64;
    const unsigned char* gB = wdescb + ((size_t)b * MPAD + n0) * 64;

    // stage: pure linear copy (global image is already interleaved+swizzled)
#pragma unroll
    for (int t = 0; t < 2; ++t) {
        gload_lds16(gA + t * 4096 + tid * 16, sA + t * 4096 + tid * 16);
        gload_lds16(gB + t * 4096 + tid * 16, sB + t * 4096 + tid * 16);
    }
    if (tid < 128) swc[tid] = wcent[b * MPAD + m0 + tid];

    const int wr = wv >> 1, wcs = wv & 1;     // wave -> 64x64 subtile
    const int frow = lane & 15;
    const int kg16 = (lane >> 4) * 16;        // 16B group index * 16

    // ---- pre-barrier independent work (hides under staging vmcnt) ----
    float cyv[4], cxv[4], vmv[4];
#pragma unroll
    for (int fj = 0; fj < 4; ++fj) {
        int col = n0 + wcs * 64 + fj * 16 + frow;
        int k = div60(col);
        int l = col - k * WCC;
        cyv[fj] = (float)(k * 8 + 4);
        cxv[fj] = (float)(l * 8 + 4);
        vmv[fj] = (col < NCELL) ? vm[b * NCELL + col] : 0.f;
    }
    float wyl = wcent[b * MPAD + m0 + wr * 64 + lane].x;
    float wlo = wyl, whi = wyl;
#pragma unroll
    for (int off = 32; off > 0; off >>= 1) {
        wlo = fminf(wlo, __shfl_xor(wlo, off));
        whi = fmaxf(whi, __shfl_xor(whi, off));
    }
    int c0 = n0 + wcs * 64;
    float cy0 = (float)(div60(c0) * 8 + 4) - 7.5f;
    float cy1 = (float)(div60(c0 + 63) * 8 + 4) + 7.5f;
    bool full = (whi >= cy0) && (wlo <= cy1);

    __syncthreads();

    // fragments: one 16B read per (matrix, f) = both k-halves
    u64x2 afr[4], bfr[4];
#pragma unroll
    for (int f = 0; f < 4; ++f) {
        int ra = wr * 64 + f * 16 + frow;
        afr[f] = *(const u64x2*)(sA + ra * 64 + (kg16 ^ ((ra & 3) << 4)));
        int rb = wcs * 64 + f * 16 + frow;
        bfr[f] = *(const u64x2*)(sB + rb * 64 + (kg16 ^ ((rb & 3) << 4)));
    }

    f32x4 acc[4][4];
#pragma unroll
    for (int i2 = 0; i2 < 4; ++i2)
#pragma unroll
        for (int j2 = 0; j2 < 4; ++j2)
            acc[i2][j2] = (f32x4)(0.f);

#pragma unroll
    for (int kk = 0; kk < 2; ++kk)
#pragma unroll
        for (int fi = 0; fi < 4; ++fi)
#pragma unroll
            for (int fj = 0; fj < 4; ++fj)
                acc[fi][fj] = __builtin_amdgcn_mfma_f32_16x16x32_fp8_fp8(
                    (long long)afr[fi][kk], (long long)bfr[fj][kk],
                    acc[fi][fj], 0, 0, 0);

    // ---- max-form epilogue: vm*max(dot,0.2); s=1 -> vm*(250*relu(1-dot)+0.2) ----
    float partial = 0.f;
    if (full) {
#pragma unroll
        for (int fi = 0; fi < 4; ++fi) {
#pragma unroll
            for (int q = 0; q < 4; ++q) {
                float2 w2 = swc[wr * 64 + fi * 16 + (lane >> 4) * 4 + q];
#pragma unroll
                for (int fj = 0; fj < 4; ++fj) {
                    float dot = acc[fi][fj][q];
                    float ddy = cyv[fj] - w2.x;
                    float ddx = cxv[fj] - w2.y;
                    float d2 = ddy * ddy + ddx * ddx;
                    float pos = 250.f * fmaxf(1.f - dot, 0.f) + 0.2f;
                    float neg = fmaxf(dot, 0.2f);
                    partial += vmv[fj] * ((d2 <= 56.25f) ? pos : neg);
                }
            }
        }
    } else {
#pragma unroll
        for (int fj = 0; fj < 4; ++fj) {
            float cs = 0.f;
#pragma unroll
            for (int fi = 0; fi < 4; ++fi)
#pragma unroll
                for (int q = 0; q < 4; ++q)
                    cs += fmaxf(acc[fi][fj][q], 0.2f);
            partial = fmaf(vmv[fj], cs, partial);
        }
    }

#pragma unroll
    for (int off = 32; off > 0; off >>= 1) partial += __shfl_xor(partial, off);
    if (lane == 0) swave[wv] = partial;
    __syncthreads();
    if (tid == 0)
        gpart[orig] = swave[0] + swave[1] + swave[2] + swave[3];
}

// ---- kernel 3: final reduction -> scalar (applies the -0.2 max-form correction) ----
__global__ __launch_bounds__(256) void dl_final_kernel(
    const float* __restrict__ vpart, const float* __restrict__ gpart,
    float* __restrict__ out)
{
    int tid = threadIdx.x;
    float ls = 0.f, vs = 0.f;
    for (int i = tid; i < GEMM_BLOCKS; i += 256) ls += gpart[i];
    for (int i = tid; i < VM_BLOCKS; i += 256) vs += vpart[i];
#pragma unroll
    for (int off = 32; off > 0; off >>= 1) {
        ls += __shfl_xor(ls, off);
        vs += __shfl_xor(vs, off);
    }
    __shared__ float sl[4], sv[4];
    if ((tid & 63) == 0) { sl[tid >> 6] = ls; sv[tid >> 6] = vs; }
    __syncthreads();
    if (tid == 0) {
        float L = sl[0] + sl[1] + sl[2] + sl[3];
        float V = sv[0] + sv[1] + sv[2] + sv[3];
        L -= 0.2f * (float)MPAD * V;          // max-form global correction (768*V)
        out[0] = L / (V * (float)NCELL);
    }
}

extern "C" void kernel_launch(void* const* d_in, const int* in_sizes, int n_in,
                              void* d_out, int out_size, void* d_ws, size_t ws_size,
                              hipStream_t stream) {
    const float* desc  = (const float*)d_in[0];
    const float* wdesc = (const float*)d_in[1];
    const float* homog = (const float*)d_in[2];
    const float* mask  = (const float*)d_in[3];
    float* out = (float*)d_out;
    float* wsf = (float*)d_ws;

    // workspace layout (floats); every slot fully overwritten each call
    float* vpart = wsf;                           // [57]
    float* vm    = wsf + 64;                      // [14400]
    float* gpart = wsf + 64 + NBC;                // [3600] -> ends at 18064
    float2* wcent = (float2*)(wsf + 18064);       // [4*3840] float2, 8B aligned
    unsigned char* descb  = (unsigned char*)(wsf + 48896);     // fp8 [4*3840*64] B
    unsigned char* wdescb = descb + (size_t)4 * MPAD * 64;

    hipLaunchKernelGGL(dl_prep_kernel, dim3(PREP_BLOCKS), dim3(256), 0, stream,
                       desc, wdesc, homog, mask, descb, wdescb, vm, vpart, wcent);
    hipLaunchKernelGGL(dl_gemm_loss_kernel, dim3(GEMM_BLOCKS), dim3(256), 0, stream,
                       descb, wdescb, vm, wcent, gpart);
    hipLaunchKernelGGL(dl_final_kernel, dim3(1), dim3(256), 0, stream,
                       vpart, gpart, out);
}